// Round 12
// baseline (226.143 us; speedup 1.0000x reference)
//
#include <hip/hip_runtime.h>
#include <hip/hip_bf16.h>

namespace {

constexpr int E_DIM = 512;
constexpr int NH = 8;
constexpr int HD = 64;
constexpr int LQ = 1024;
constexpr int LKV = 4096;
constexpr int NB = 4;
constexpr int SPLIT = 4;           // kv splits (256 blocks = 1/CU, co-resident)
constexpr int SLICE = LKV / SPLIT; // 1024
constexpr int NT = SLICE / 64;     // 16 tiles per block
constexpr size_t CPL = (size_t)NB * LQ * E_DIM;  // ctx plane elems (2M)

typedef __attribute__((ext_vector_type(8))) short bf16x8;
typedef __attribute__((ext_vector_type(8))) unsigned short u16x8;
typedef __attribute__((ext_vector_type(4))) float f32x4;

typedef const unsigned int __attribute__((address_space(1)))* gptr1;
typedef unsigned int __attribute__((address_space(3)))* lptr3;

__device__ __forceinline__ void gl16(const unsigned short* g, unsigned short* l) {
  __builtin_amdgcn_global_load_lds((gptr1)g, (lptr3)l, 16, 0, 0);
}

__device__ __forceinline__ f32x4 mfma16(bf16x8 a, bf16x8 b, f32x4 c) {
  return __builtin_amdgcn_mfma_f32_16x16x32_bf16(a, b, c, 0, 0, 0);
}

// f32 -> bf16 bits, round-to-nearest-even (finite inputs only)
__device__ __forceinline__ unsigned short f2b(float f) {
  unsigned int u = __float_as_uint(f);
  u += 0x7FFFu + ((u >> 16) & 1u);
  return (unsigned short)(u >> 16);
}

__device__ __forceinline__ unsigned int cvt_pk_bf16(float a, float b) {
  unsigned int r;
  asm("v_cvt_pk_bf16_f32 %0, %1, %2" : "=v"(r) : "v"(a), "v"(b));
  return r;
}

// ---- one-shot f32 -> bf16 conversion of query, key_value, and 4 weights ----
__global__ __launch_bounds__(256) void cvt_all(
    const float* __restrict__ query, const float* __restrict__ kv,
    const float* __restrict__ w0, const float* __restrict__ w1,
    const float* __restrict__ w2, const float* __restrict__ w3,
    unsigned short* __restrict__ Qxb, unsigned short* __restrict__ KVb,
    unsigned short* __restrict__ Wb) {
  const int blk = blockIdx.x;
  const float* s;
  unsigned short* d;
  size_t idx;
  if (blk < 1024) {
    idx = ((size_t)blk * 256 + threadIdx.x) * 8;
    s = query; d = Qxb;
  } else if (blk < 5120) {
    idx = ((size_t)(blk - 1024) * 256 + threadIdx.x) * 8;
    s = kv; d = KVb;
  } else {
    idx = ((size_t)(blk - 5120) * 256 + threadIdx.x) * 8;
    const int widx = (int)(idx >> 18);
    s = widx == 0 ? w0 : widx == 1 ? w1 : widx == 2 ? w2 : w3;
    d = Wb;
    s -= (size_t)widx << 18;
  }
  const float4 a = *(const float4*)(s + idx);
  const float4 b = *(const float4*)(s + idx + 4);
  uint4 o;
  o.x = cvt_pk_bf16(a.x, a.y);
  o.y = cvt_pk_bf16(a.z, a.w);
  o.z = cvt_pk_bf16(b.x, b.y);
  o.w = cvt_pk_bf16(b.z, b.w);
  *(uint4*)(d + idx) = o;
}

// ---- bf16 GEMM, 128x128 tile, BK=32, global_load_lds staging ---------------
// EPI 0: bf16 head-split; EPI 2: f32 plain
template <int EPI>
__global__ __launch_bounds__(256) void gemm_bf16(
    const unsigned short* __restrict__ A, const unsigned short* __restrict__ B,
    const float* __restrict__ bias, void* __restrict__ outp, int L,
    float oscale) {
  __shared__ __align__(16) unsigned short As[128][32];
  __shared__ __align__(16) unsigned short Bs[128][32];
  const int tid = threadIdx.x;
  const int wv = tid >> 6, lane = tid & 63, lg = lane >> 4, lr = lane & 15;
  const int gx = gridDim.x, gy = gridDim.y;
  const int p = blockIdx.x + gx * blockIdx.y;
  const int xcd = p & 7, ii = p >> 3;
  const int by = xcd * (gy >> 3) + ii / gx;
  const int bx = ii - (ii / gx) * gx;
  const int i0 = by * 128, j0 = bx * 128;
  const int wm = wv >> 1, wn = wv & 1;
  const int srow = tid >> 2, scol = (tid & 3) * 8;
  f32x4 acc[4][4] = {};
  const unsigned short* ap = A + (size_t)(i0 + srow) * E_DIM + scol;
  const unsigned short* bp = B + (size_t)(j0 + srow) * E_DIM + scol;
  unsigned short* lA = &As[srow][scol];
  unsigned short* lB = &Bs[srow][scol];
  for (int k0 = 0; k0 < E_DIM; k0 += 32) {
    __syncthreads();
    gl16(ap + k0, lA);
    gl16(ap + k0 + (size_t)64 * E_DIM, lA + 64 * 32);
    gl16(bp + k0, lB);
    gl16(bp + k0 + (size_t)64 * E_DIM, lB + 64 * 32);
    __syncthreads();
    bf16x8 af[4], bg[4];
    for (int m = 0; m < 4; ++m)
      af[m] = *(const bf16x8*)&As[wm * 64 + m * 16 + lr][lg * 8];
    for (int n = 0; n < 4; ++n)
      bg[n] = *(const bf16x8*)&Bs[wn * 64 + n * 16 + lr][lg * 8];
    for (int m = 0; m < 4; ++m)
      for (int n = 0; n < 4; ++n)
        acc[m][n] = mfma16(af[m], bg[n], acc[m][n]);
  }
  for (int m = 0; m < 4; ++m)
    for (int n = 0; n < 4; ++n) {
      const int j = j0 + wn * 64 + n * 16 + lr;
      const float bj = bias[j];
      for (int r = 0; r < 4; ++r) {
        const int i = i0 + wm * 64 + m * 16 + lg * 4 + r;
        const float v = (acc[m][n][r] + bj) * oscale;
        if (EPI == 2) {
          ((float*)outp)[(size_t)i * E_DIM + j] = v;
        } else {
          const int bb = i / L, li = i - bb * L;
          const int hh = j >> 6, dd = j & 63;
          ((unsigned short*)outp)[((size_t)(bb * NH + hh) * L + li) * HD + dd] = f2b(v);
        }
      }
    }
}

// ---- fused K+V projection: one block computes K-tile AND V-tile (shared A)
// K: bf16 head-split  Kb[((b*NH+h)*LKV + l)*64 + d]
// V: bf16 head-split transposed, x8  Vt[((b*NH+h)*64 + d)*LKV + l]
__global__ __launch_bounds__(256) void gemm_kv(
    const unsigned short* __restrict__ A, const unsigned short* __restrict__ Bk,
    const unsigned short* __restrict__ Bv, const float* __restrict__ bk,
    const float* __restrict__ bv, unsigned short* __restrict__ Kb,
    unsigned short* __restrict__ Vt) {
  __shared__ __align__(16) unsigned short As[128][32];
  __shared__ __align__(16) unsigned short Bks[128][32];
  __shared__ __align__(16) unsigned short Bvs[128][32];
  const int tid = threadIdx.x;
  const int wv = tid >> 6, lane = tid & 63, lg = lane >> 4, lr = lane & 15;
  const int gx = gridDim.x, gy = gridDim.y;  // (4, 128)
  const int p = blockIdx.x + gx * blockIdx.y;
  const int xcd = p & 7, ii = p >> 3;
  const int by = xcd * (gy >> 3) + ii / gx;
  const int bx = ii - (ii / gx) * gx;
  const int i0 = by * 128, j0 = bx * 128;
  const int wm = wv >> 1, wn = wv & 1;
  const int srow = tid >> 2, scol = (tid & 3) * 8;
  f32x4 acck[4][4] = {}, accv[4][4] = {};
  const unsigned short* ap = A + (size_t)(i0 + srow) * E_DIM + scol;
  const unsigned short* bkp = Bk + (size_t)(j0 + srow) * E_DIM + scol;
  const unsigned short* bvp = Bv + (size_t)(j0 + srow) * E_DIM + scol;
  unsigned short* lA = &As[srow][scol];
  unsigned short* lBk = &Bks[srow][scol];
  unsigned short* lBv = &Bvs[srow][scol];
  for (int k0 = 0; k0 < E_DIM; k0 += 32) {
    __syncthreads();
    gl16(ap + k0, lA);
    gl16(ap + k0 + (size_t)64 * E_DIM, lA + 64 * 32);
    gl16(bkp + k0, lBk);
    gl16(bkp + k0 + (size_t)64 * E_DIM, lBk + 64 * 32);
    gl16(bvp + k0, lBv);
    gl16(bvp + k0 + (size_t)64 * E_DIM, lBv + 64 * 32);
    __syncthreads();
    bf16x8 af[4], bgk[4], bgv[4];
    for (int m = 0; m < 4; ++m)
      af[m] = *(const bf16x8*)&As[wm * 64 + m * 16 + lr][lg * 8];
    for (int n = 0; n < 4; ++n) {
      bgk[n] = *(const bf16x8*)&Bks[wn * 64 + n * 16 + lr][lg * 8];
      bgv[n] = *(const bf16x8*)&Bvs[wn * 64 + n * 16 + lr][lg * 8];
    }
    for (int m = 0; m < 4; ++m)
      for (int n = 0; n < 4; ++n) {
        acck[m][n] = mfma16(af[m], bgk[n], acck[m][n]);
        accv[m][n] = mfma16(af[m], bgv[n], accv[m][n]);
      }
  }
  for (int m = 0; m < 4; ++m)
    for (int n = 0; n < 4; ++n) {
      const int j = j0 + wn * 64 + n * 16 + lr;
      const float bkj = bk[j], bvj = bv[j];
      const int hh = j >> 6, dd = j & 63;
      for (int r = 0; r < 4; ++r) {
        const int i = i0 + wm * 64 + m * 16 + lg * 4 + r;
        const int bb = i / LKV, li = i - bb * LKV;
        Kb[((size_t)(bb * NH + hh) * LKV + li) * HD + dd] = f2b(acck[m][n][r] + bkj);
        // V pre-scaled x8 (pairs with P/8 so PV is exact)
        Vt[((size_t)(bb * NH + hh) * HD + dd) * LKV + li] =
            f2b((accv[m][n][r] + bvj) * 8.0f);
      }
    }
}

// ---- Fused attention: prologue (own-slice row sums) + 4-way flag sync +
//      main (P, PV, head-avg). Grid MUST be 256 = 1 block/CU (128 KB LDS)
//      so all blocks are co-resident; the flag spin is deadlock-free.
//      FROZEN: byte-identical to the R9 passing build. Do not touch.
__global__ __launch_bounds__(512) void attn_fused(
    const unsigned short* __restrict__ Qb, const unsigned short* __restrict__ Kb,
    const unsigned short* __restrict__ Vt, float* __restrict__ l_part,
    int* __restrict__ flags, float* __restrict__ attn_w,
    unsigned short* __restrict__ ctxp) {
  __shared__ __align__(16) unsigned short P[2][NH][64][64];  // 128 KB dbuf
  const int tid = threadIdx.x;
  const int h = tid >> 6, lane = tid & 63, lg = lane >> 4, lr = lane & 15;
  const int p = blockIdx.x + 16 * blockIdx.y + 64 * blockIdx.z;
  const int xcd = p & 7, ii = p >> 3;
  const int combo = xcd * 2 + (ii >> 4);
  const int qg = ii & 15;           // q-group index (q0 = qg*64)
  const int q0 = qg * 64;
  const int b = combo >> 2, sp = combo & 3;
  const size_t bh = (size_t)b * NH + h;
  const unsigned short* Qp = Qb + (bh * LQ + q0) * HD;
  const unsigned short* Kp = Kb + (bh * LKV + sp * SLICE) * HD;
  const unsigned short* Vp = Vt + bh * HD * LKV + sp * SLICE;

  bf16x8 qB[4][2];
  for (int qs = 0; qs < 4; ++qs)
    for (int kk = 0; kk < 2; ++kk)
      qB[qs][kk] = *(const bf16x8*)(Qp + (qs * 16 + lr) * HD + kk * 32 + lg * 8);

  // ---- prologue: row sums of 2^score over this block's kv slice ----
  float qsum[4] = {};
  for (int t = 0; t < NT; ++t) {
    const unsigned short* base = Kp + (size_t)t * 64 * HD;
    for (int k2h = 0; k2h < 2; ++k2h) {
      bf16x8 kA[2][2];
      for (int k2 = 0; k2 < 2; ++k2)
        for (int kk = 0; kk < 2; ++kk)
          kA[k2][kk] = *(const bf16x8*)(base + ((k2h * 2 + k2) * 16 + lr) * HD +
                                        kk * 32 + lg * 8);
      f32x4 sacc[2][4] = {};
      for (int k2 = 0; k2 < 2; ++k2)
        for (int qs = 0; qs < 4; ++qs)
          sacc[k2][qs] = mfma16(kA[k2][1], qB[qs][1],
                                mfma16(kA[k2][0], qB[qs][0], sacc[k2][qs]));
      for (int k2 = 0; k2 < 2; ++k2)
        for (int qs = 0; qs < 4; ++qs)
          for (int r = 0; r < 4; ++r)
            qsum[qs] += __builtin_amdgcn_exp2f(sacc[k2][qs][r]);
    }
  }
  for (int qs = 0; qs < 4; ++qs) {
    float v = qsum[qs];
    v += __shfl_xor(v, 16);
    v += __shfl_xor(v, 32);
    if (lg == 0)
      l_part[(size_t)sp * (NB * NH * LQ) + bh * LQ + q0 + qs * 16 + lr] = v;
  }
  __syncthreads();
  // ---- 4-way sync among blocks sharing (b, qg) ----
  if (tid == 0) {
    __threadfence();  // publish l_part (device scope)
    int* fl = &flags[b * 16 + qg];
    __hip_atomic_fetch_add(fl, 1, __ATOMIC_ACQ_REL, __HIP_MEMORY_SCOPE_AGENT);
    while (__hip_atomic_load(fl, __ATOMIC_ACQUIRE, __HIP_MEMORY_SCOPE_AGENT) < SPLIT) {
    }
    __threadfence();
  }
  __syncthreads();

  float nlg[4];
  for (int qs = 0; qs < 4; ++qs) {
    float ls = 0.f;
    for (int s = 0; s < SPLIT; ++s)
      ls += l_part[(size_t)s * (NB * NH * LQ) + bh * LQ + q0 + qs * 16 + lr];
    nlg[qs] = -__builtin_amdgcn_logf(ls) - 3.0f;  // fold softmax/8
  }

  // ---- main: P (swizzled dbuf), PV, barrier, head-avg; 1 barrier/tile ----
  f32x4 cacc[4][4] = {};
  for (int t = 0; t < NT; ++t) {
    const int kv0 = t * 64;  // within this block's slice
    unsigned short (*Pb)[64][64] = P[t & 1];
    bf16x8 vf[4][2];
    for (int ds = 0; ds < 4; ++ds)
      for (int kk = 0; kk < 2; ++kk)
        vf[ds][kk] = *(const bf16x8*)(Vp + (size_t)(ds * 16 + lr) * LKV + kv0 +
                                      kk * 32 + lg * 8);
    for (int kh = 0; kh < 2; ++kh) {
      bf16x8 kA[2][2];
      for (int k2 = 0; k2 < 2; ++k2)
        for (int kk = 0; kk < 2; ++kk)
          kA[k2][kk] = *(const bf16x8*)(Kp + (size_t)(kv0 + (kh * 2 + k2) * 16 + lr) * HD +
                                        kk * 32 + lg * 8);
      f32x4 sacc[2][4] = {};
      for (int k2 = 0; k2 < 2; ++k2)
        for (int qs = 0; qs < 4; ++qs)
          sacc[k2][qs] = mfma16(kA[k2][1], qB[qs][1],
                                mfma16(kA[k2][0], qB[qs][0], sacc[k2][qs]));
      for (int k2 = 0; k2 < 2; ++k2)
        for (int qs = 0; qs < 4; ++qs) {
          const int q = qs * 16 + lr;
          const float p0 = __builtin_amdgcn_exp2f(sacc[k2][qs][0] + nlg[qs]);
          const float p1 = __builtin_amdgcn_exp2f(sacc[k2][qs][1] + nlg[qs]);
          const float p2 = __builtin_amdgcn_exp2f(sacc[k2][qs][2] + nlg[qs]);
          const float p3 = __builtin_amdgcn_exp2f(sacc[k2][qs][3] + nlg[qs]);
          uint2 w;
          w.x = cvt_pk_bf16(p0, p1);
          w.y = cvt_pk_bf16(p2, p3);
          const int col = ((kh * 2 + k2) * 16 + lg * 4) ^ ((q & 7) << 3);
          *(uint2*)&Pb[h][q][col] = w;
        }
    }
    // PV on own head's P (same-wave LDS dependency; no barrier needed)
    for (int kk = 0; kk < 2; ++kk) {
      bf16x8 pa[4];
      for (int qs = 0; qs < 4; ++qs) {
        const int q = qs * 16 + lr;
        pa[qs] = *(const bf16x8*)&Pb[h][q][(kk * 32 + lg * 8) ^ ((q & 7) << 3)];
      }
      for (int qs = 0; qs < 4; ++qs)
        for (int ds = 0; ds < 4; ++ds)
          cacc[qs][ds] = mfma16(pa[qs], vf[ds][kk], cacc[qs][ds]);
    }
    __syncthreads();  // all heads' P(t) visible
    // head-average -> attn_w (P already holds softmax/8)
    {
      const int qa = tid >> 3, La = tid & 7;
      const int col = (La * 8) ^ ((qa & 7) << 3);
      float2 s01 = {0.f, 0.f}, s23 = {0.f, 0.f}, s45 = {0.f, 0.f},
             s67 = {0.f, 0.f};
      for (int hh = 0; hh < NH; ++hh) {
        const uint4 v = *(const uint4*)&Pb[hh][qa][col];
        s01.x += __uint_as_float(v.x << 16);
        s01.y += __uint_as_float(v.x & 0xFFFF0000u);
        s23.x += __uint_as_float(v.y << 16);
        s23.y += __uint_as_float(v.y & 0xFFFF0000u);
        s45.x += __uint_as_float(v.z << 16);
        s45.y += __uint_as_float(v.z & 0xFFFF0000u);
        s67.x += __uint_as_float(v.w << 16);
        s67.y += __uint_as_float(v.w & 0xFFFF0000u);
      }
      float* op = attn_w + (size_t)(b * LQ + q0 + qa) * LKV + sp * SLICE + kv0 +
                  La * 8;
      float4 o0 = {s01.x, s01.y, s23.x, s23.y};
      float4 o1 = {s45.x, s45.y, s67.x, s67.y};
      *(float4*)op = o0;
      *(float4*)(op + 4) = o1;
    }
    // no second barrier: next tile writes P[(t+1)&1]
  }
  unsigned short* cp = ctxp + (size_t)sp * CPL;
  for (int qs = 0; qs < 4; ++qs)
    for (int ds = 0; ds < 4; ++ds)
      for (int r = 0; r < 4; ++r)
        cp[(size_t)(b * LQ + q0 + qs * 16 + lg * 4 + r) * E_DIM + h * HD +
           ds * 16 + lr] = f2b(cacc[qs][ds][r]);
}

// sum 4 bf16 ctx planes -> bf16 ctx
__global__ __launch_bounds__(256) void combine_ctx(
    const unsigned short* __restrict__ ctxp, unsigned short* __restrict__ ctxb) {
  const size_t i = (size_t)blockIdx.x * 256 + threadIdx.x;  // 8 elems/thread
  float2 s01 = {0.f, 0.f}, s23 = {0.f, 0.f}, s45 = {0.f, 0.f}, s67 = {0.f, 0.f};
  for (int pl = 0; pl < SPLIT; ++pl) {
    const uint4 v = ((const uint4*)(ctxp + pl * CPL))[i];
    s01.x += __uint_as_float(v.x << 16);
    s01.y += __uint_as_float(v.x & 0xFFFF0000u);
    s23.x += __uint_as_float(v.y << 16);
    s23.y += __uint_as_float(v.y & 0xFFFF0000u);
    s45.x += __uint_as_float(v.z << 16);
    s45.y += __uint_as_float(v.z & 0xFFFF0000u);
    s67.x += __uint_as_float(v.w << 16);
    s67.y += __uint_as_float(v.w & 0xFFFF0000u);
  }
  uint4 o;
  o.x = cvt_pk_bf16(s01.x, s01.y);
  o.y = cvt_pk_bf16(s23.x, s23.y);
  o.z = cvt_pk_bf16(s45.x, s45.y);
  o.w = cvt_pk_bf16(s67.x, s67.y);
  ((uint4*)ctxb)[i] = o;
}

// out = LN(query + attn_out) * gamma + beta ; one block per row
__global__ __launch_bounds__(256) void ln_kernel(
    const float* __restrict__ q, const float* __restrict__ ao,
    const float* __restrict__ gamma, const float* __restrict__ beta,
    float* __restrict__ out) {
  const int row = blockIdx.x;
  const int tid = threadIdx.x;
  const size_t base = (size_t)row * E_DIM;
  const float x0 = q[base + tid] + ao[base + tid];
  const float x1 = q[base + 256 + tid] + ao[base + 256 + tid];
  float s = x0 + x1, ss = x0 * x0 + x1 * x1;
  for (int off = 32; off >= 1; off >>= 1) {
    s += __shfl_down(s, off);
    ss += __shfl_down(ss, off);
  }
  __shared__ float ps[4], pss[4];
  if ((tid & 63) == 0) {
    ps[tid >> 6] = s;
    pss[tid >> 6] = ss;
  }
  __syncthreads();
  s = ps[0] + ps[1] + ps[2] + ps[3];
  ss = pss[0] + pss[1] + pss[2] + pss[3];
  const float mu = s * (1.f / E_DIM);
  float var = ss * (1.f / E_DIM) - mu * mu;
  var = fmaxf(var, 0.f);
  const float rstd = rsqrtf(var + 1e-5f);
  out[base + tid] = (x0 - mu) * rstd * gamma[tid] + beta[tid];
  out[base + 256 + tid] = (x1 - mu) * rstd * gamma[256 + tid] + beta[256 + tid];
}

}  // namespace

extern "C" void kernel_launch(void* const* d_in, const int* in_sizes, int n_in,
                              void* d_out, int out_size, void* d_ws, size_t ws_size,
                              hipStream_t stream) {
  const float* query = (const float*)d_in[0];
  const float* key_value = (const float*)d_in[1];
  const float* w_q = (const float*)d_in[2];
  const float* w_k = (const float*)d_in[3];
  const float* w_v = (const float*)d_in[4];
  const float* b_q = (const float*)d_in[5];
  const float* b_k = (const float*)d_in[6];
  const float* b_v = (const float*)d_in[7];
  const float* w_o = (const float*)d_in[8];
  const float* b_o = (const float*)d_in[9];
  const float* ln_g = (const float*)d_in[10];
  const float* ln_b = (const float*)d_in[11];

  // ws layout in u16 units (65 MB peak):
  // Qb[0,2M) Kb[2M,10M) Vt[10M,18M) l_part+flags[18M,18.5M) Wb[18.5M,19.5M)
  // ao(f32)[19.5M,23.5M) KVb[23.5M,31.5M) Qxb[31.5M,32.5M)
  // ctxp aliases KVb [23.5M,31.5M) (4 planes; KVb dead after GEMMs)
  // ctxb aliases Qb [0,2M)         (Qb dead after attn_fused)
  unsigned short* Qb = (unsigned short*)d_ws;
  unsigned short* Kb = Qb + (size_t)2097152;
  unsigned short* Vt = Kb + (size_t)8388608;
  float* l_part = (float*)(Vt + (size_t)8388608);
  int* flags = (int*)(l_part + (size_t)SPLIT * NB * NH * LQ);  // 64 ints
  unsigned short* Wb = (unsigned short*)(l_part + 262144);
  float* ao = (float*)(Wb + 1048576);
  unsigned short* KVb = (unsigned short*)(ao + 2097152);
  unsigned short* Qxb = KVb + (size_t)8388608;
  unsigned short* ctxp = KVb;  // alias (KVb dead after GEMMs)
  unsigned short* ctxb = Qb;   // alias (Qb dead after attn_fused)

  float* out = (float*)d_out;
  float* attn_w = out + (size_t)NB * LQ * E_DIM;

  const float qscale = 0.125f * 1.44269504088896340736f;  // 1/sqrt(64)*log2(e)

  hipMemsetAsync(flags, 0, sizeof(int) * NB * 16, stream);

  cvt_all<<<dim3(5632), dim3(256), 0, stream>>>(query, key_value, w_q, w_k, w_v,
                                                w_o, Qxb, KVb, Wb);

  gemm_bf16<0><<<dim3(4, 32), dim3(256), 0, stream>>>(Qxb, Wb, b_q, Qb, LQ, qscale);
  // fused K+V projection: shared A staging, one dispatch
  gemm_kv<<<dim3(4, 128), dim3(256), 0, stream>>>(KVb, Wb + 262144, Wb + 524288,
                                                  b_k, b_v, Kb, Vt);

  attn_fused<<<dim3(16, NB, SPLIT), dim3(512), 0, stream>>>(Qb, Kb, Vt, l_part,
                                                            flags, attn_w, ctxp);
  combine_ctx<<<dim3(1024), dim3(256), 0, stream>>>(ctxp, ctxb);
  gemm_bf16<2><<<dim3(4, 32), dim3(256), 0, stream>>>(ctxb, Wb + 786432, b_o, ao,
                                                      LQ, 1.0f);
  ln_kernel<<<dim3(NB * LQ), dim3(256), 0, stream>>>(query, ao, ln_g, ln_b, out);
}

// Round 14
// 215.324 us; speedup vs baseline: 1.0502x; 1.0502x over previous
//
#include <hip/hip_runtime.h>
#include <hip/hip_bf16.h>

namespace {

constexpr int E_DIM = 512;
constexpr int NH = 8;
constexpr int HD = 64;
constexpr int LQ = 1024;
constexpr int LKV = 4096;
constexpr int NB = 4;
constexpr int SPLIT = 4;           // kv splits (256 blocks = 1/CU, co-resident)
constexpr int SLICE = LKV / SPLIT; // 1024
constexpr int NT = SLICE / 64;     // 16 tiles per block
constexpr size_t CPL = (size_t)NB * LQ * E_DIM;  // ctx plane elems (2M)

typedef __attribute__((ext_vector_type(8))) short bf16x8;
typedef __attribute__((ext_vector_type(8))) unsigned short u16x8;
typedef __attribute__((ext_vector_type(4))) float f32x4;

typedef const unsigned int __attribute__((address_space(1)))* gptr1;
typedef unsigned int __attribute__((address_space(3)))* lptr3;

__device__ __forceinline__ void gl16(const unsigned short* g, unsigned short* l) {
  __builtin_amdgcn_global_load_lds((gptr1)g, (lptr3)l, 16, 0, 0);
}

__device__ __forceinline__ f32x4 mfma16(bf16x8 a, bf16x8 b, f32x4 c) {
  return __builtin_amdgcn_mfma_f32_16x16x32_bf16(a, b, c, 0, 0, 0);
}

// f32 -> bf16 bits, round-to-nearest-even (finite inputs only)
__device__ __forceinline__ unsigned short f2b(float f) {
  unsigned int u = __float_as_uint(f);
  u += 0x7FFFu + ((u >> 16) & 1u);
  return (unsigned short)(u >> 16);
}

__device__ __forceinline__ unsigned int cvt_pk_bf16(float a, float b) {
  unsigned int r;
  asm("v_cvt_pk_bf16_f32 %0, %1, %2" : "=v"(r) : "v"(a), "v"(b));
  return r;
}

// ---- one-shot f32 -> bf16 conversion of query, key_value, and 4 weights ----
__global__ __launch_bounds__(256) void cvt_all(
    const float* __restrict__ query, const float* __restrict__ kv,
    const float* __restrict__ w0, const float* __restrict__ w1,
    const float* __restrict__ w2, const float* __restrict__ w3,
    unsigned short* __restrict__ Qxb, unsigned short* __restrict__ KVb,
    unsigned short* __restrict__ Wb) {
  const int blk = blockIdx.x;
  const float* s;
  unsigned short* d;
  size_t idx;
  if (blk < 1024) {
    idx = ((size_t)blk * 256 + threadIdx.x) * 8;
    s = query; d = Qxb;
  } else if (blk < 5120) {
    idx = ((size_t)(blk - 1024) * 256 + threadIdx.x) * 8;
    s = kv; d = KVb;
  } else {
    idx = ((size_t)(blk - 5120) * 256 + threadIdx.x) * 8;
    const int widx = (int)(idx >> 18);
    s = widx == 0 ? w0 : widx == 1 ? w1 : widx == 2 ? w2 : w3;
    d = Wb;
    s -= (size_t)widx << 18;
  }
  const float4 a = *(const float4*)(s + idx);
  const float4 b = *(const float4*)(s + idx + 4);
  uint4 o;
  o.x = cvt_pk_bf16(a.x, a.y);
  o.y = cvt_pk_bf16(a.z, a.w);
  o.z = cvt_pk_bf16(b.x, b.y);
  o.w = cvt_pk_bf16(b.z, b.w);
  *(uint4*)(d + idx) = o;
}

// ---- bf16 GEMM, 128x128 tile, BK=32, global_load_lds staging ---------------
// EPI 0: bf16 head-split; EPI 1: bf16 head-split transposed; EPI 2: f32 plain
template <int EPI>
__global__ __launch_bounds__(256) void gemm_bf16(
    const unsigned short* __restrict__ A, const unsigned short* __restrict__ B,
    const float* __restrict__ bias, void* __restrict__ outp, int L,
    float oscale) {
  __shared__ __align__(16) unsigned short As[128][32];
  __shared__ __align__(16) unsigned short Bs[128][32];
  const int tid = threadIdx.x;
  const int wv = tid >> 6, lane = tid & 63, lg = lane >> 4, lr = lane & 15;
  const int gx = gridDim.x, gy = gridDim.y;
  const int p = blockIdx.x + gx * blockIdx.y;
  const int xcd = p & 7, ii = p >> 3;
  const int by = xcd * (gy >> 3) + ii / gx;
  const int bx = ii - (ii / gx) * gx;
  const int i0 = by * 128, j0 = bx * 128;
  const int wm = wv >> 1, wn = wv & 1;
  const int srow = tid >> 2, scol = (tid & 3) * 8;
  f32x4 acc[4][4] = {};
  const unsigned short* ap = A + (size_t)(i0 + srow) * E_DIM + scol;
  const unsigned short* bp = B + (size_t)(j0 + srow) * E_DIM + scol;
  unsigned short* lA = &As[srow][scol];
  unsigned short* lB = &Bs[srow][scol];
  for (int k0 = 0; k0 < E_DIM; k0 += 32) {
    __syncthreads();
    gl16(ap + k0, lA);
    gl16(ap + k0 + (size_t)64 * E_DIM, lA + 64 * 32);
    gl16(bp + k0, lB);
    gl16(bp + k0 + (size_t)64 * E_DIM, lB + 64 * 32);
    __syncthreads();
    bf16x8 af[4], bg[4];
    for (int m = 0; m < 4; ++m)
      af[m] = *(const bf16x8*)&As[wm * 64 + m * 16 + lr][lg * 8];
    for (int n = 0; n < 4; ++n)
      bg[n] = *(const bf16x8*)&Bs[wn * 64 + n * 16 + lr][lg * 8];
    for (int m = 0; m < 4; ++m)
      for (int n = 0; n < 4; ++n)
        acc[m][n] = mfma16(af[m], bg[n], acc[m][n]);
  }
  for (int m = 0; m < 4; ++m)
    for (int n = 0; n < 4; ++n) {
      const int j = j0 + wn * 64 + n * 16 + lr;
      const float bj = bias[j];
      for (int r = 0; r < 4; ++r) {
        const int i = i0 + wm * 64 + m * 16 + lg * 4 + r;
        const float v = (acc[m][n][r] + bj) * oscale;
        if (EPI == 2) {
          ((float*)outp)[(size_t)i * E_DIM + j] = v;
        } else {
          const int bb = i / L, li = i - bb * L;
          const int hh = j >> 6, dd = j & 63;
          if (EPI == 0)
            ((unsigned short*)outp)[((size_t)(bb * NH + hh) * L + li) * HD + dd] = f2b(v);
          else
            ((unsigned short*)outp)[((size_t)(bb * NH + hh) * HD + dd) * L + li] = f2b(v);
        }
      }
    }
}

// ---- bf16 GEMM, 64x128 tile (for M=4096 -> 256 blocks, full CU coverage) ---
// 4 waves, each owns 64x32. EPI 0: bf16 head-split; EPI 2: f32 plain.
template <int EPI>
__global__ __launch_bounds__(256) void gemm64(
    const unsigned short* __restrict__ A, const unsigned short* __restrict__ B,
    const float* __restrict__ bias, void* __restrict__ outp, int L,
    float oscale) {
  __shared__ __align__(16) unsigned short As[64][32];
  __shared__ __align__(16) unsigned short Bs[128][32];
  const int tid = threadIdx.x;
  const int wv = tid >> 6, lane = tid & 63, lg = lane >> 4, lr = lane & 15;
  const int gx = gridDim.x, gy = gridDim.y;  // (4, 64)
  const int p = blockIdx.x + gx * blockIdx.y;
  const int xcd = p & 7, ii = p >> 3;
  const int by = xcd * (gy >> 3) + ii / gx;
  const int bx = ii - (ii / gx) * gx;
  const int i0 = by * 64, j0 = bx * 128;
  const int srow = tid >> 2, scol = (tid & 3) * 8;
  f32x4 acc[4][2] = {};
  const unsigned short* ap = A + (size_t)(i0 + srow) * E_DIM + scol;
  const unsigned short* bp = B + (size_t)(j0 + srow) * E_DIM + scol;
  unsigned short* lA = &As[srow][scol];
  unsigned short* lB = &Bs[srow][scol];
  for (int k0 = 0; k0 < E_DIM; k0 += 32) {
    __syncthreads();
    gl16(ap + k0, lA);
    gl16(bp + k0, lB);
    gl16(bp + k0 + (size_t)64 * E_DIM, lB + 64 * 32);
    __syncthreads();
    bf16x8 af[4], bg[2];
    for (int m = 0; m < 4; ++m)
      af[m] = *(const bf16x8*)&As[m * 16 + lr][lg * 8];
    for (int n = 0; n < 2; ++n)
      bg[n] = *(const bf16x8*)&Bs[wv * 32 + n * 16 + lr][lg * 8];
    for (int m = 0; m < 4; ++m)
      for (int n = 0; n < 2; ++n)
        acc[m][n] = mfma16(af[m], bg[n], acc[m][n]);
  }
  for (int m = 0; m < 4; ++m)
    for (int n = 0; n < 2; ++n) {
      const int j = j0 + wv * 32 + n * 16 + lr;
      const float bj = bias[j];
      for (int r = 0; r < 4; ++r) {
        const int i = i0 + m * 16 + lg * 4 + r;
        const float v = (acc[m][n][r] + bj) * oscale;
        if (EPI == 2) {
          ((float*)outp)[(size_t)i * E_DIM + j] = v;
        } else {
          const int bb = i / L, li = i - bb * L;
          const int hh = j >> 6, dd = j & 63;
          ((unsigned short*)outp)[((size_t)(bb * NH + hh) * L + li) * HD + dd] = f2b(v);
        }
      }
    }
}

// ---- Fused attention: prologue (own-slice row sums) + 4-way flag sync +
//      main (P, PV, head-avg). Grid MUST be 256 = 1 block/CU (128 KB LDS)
//      so all blocks are co-resident; the flag spin is deadlock-free.
//      FROZEN: byte-identical to the R9/R12 passing builds. Do not touch.
__global__ __launch_bounds__(512) void attn_fused(
    const unsigned short* __restrict__ Qb, const unsigned short* __restrict__ Kb,
    const unsigned short* __restrict__ Vt, float* __restrict__ l_part,
    int* __restrict__ flags, float* __restrict__ attn_w,
    unsigned short* __restrict__ ctxp) {
  __shared__ __align__(16) unsigned short P[2][NH][64][64];  // 128 KB dbuf
  const int tid = threadIdx.x;
  const int h = tid >> 6, lane = tid & 63, lg = lane >> 4, lr = lane & 15;
  const int p = blockIdx.x + 16 * blockIdx.y + 64 * blockIdx.z;
  const int xcd = p & 7, ii = p >> 3;
  const int combo = xcd * 2 + (ii >> 4);
  const int qg = ii & 15;           // q-group index (q0 = qg*64)
  const int q0 = qg * 64;
  const int b = combo >> 2, sp = combo & 3;
  const size_t bh = (size_t)b * NH + h;
  const unsigned short* Qp = Qb + (bh * LQ + q0) * HD;
  const unsigned short* Kp = Kb + (bh * LKV + sp * SLICE) * HD;
  const unsigned short* Vp = Vt + bh * HD * LKV + sp * SLICE;

  bf16x8 qB[4][2];
  for (int qs = 0; qs < 4; ++qs)
    for (int kk = 0; kk < 2; ++kk)
      qB[qs][kk] = *(const bf16x8*)(Qp + (qs * 16 + lr) * HD + kk * 32 + lg * 8);

  // ---- prologue: row sums of 2^score over this block's kv slice ----
  float qsum[4] = {};
  for (int t = 0; t < NT; ++t) {
    const unsigned short* base = Kp + (size_t)t * 64 * HD;
    for (int k2h = 0; k2h < 2; ++k2h) {
      bf16x8 kA[2][2];
      for (int k2 = 0; k2 < 2; ++k2)
        for (int kk = 0; kk < 2; ++kk)
          kA[k2][kk] = *(const bf16x8*)(base + ((k2h * 2 + k2) * 16 + lr) * HD +
                                        kk * 32 + lg * 8);
      f32x4 sacc[2][4] = {};
      for (int k2 = 0; k2 < 2; ++k2)
        for (int qs = 0; qs < 4; ++qs)
          sacc[k2][qs] = mfma16(kA[k2][1], qB[qs][1],
                                mfma16(kA[k2][0], qB[qs][0], sacc[k2][qs]));
      for (int k2 = 0; k2 < 2; ++k2)
        for (int qs = 0; qs < 4; ++qs)
          for (int r = 0; r < 4; ++r)
            qsum[qs] += __builtin_amdgcn_exp2f(sacc[k2][qs][r]);
    }
  }
  for (int qs = 0; qs < 4; ++qs) {
    float v = qsum[qs];
    v += __shfl_xor(v, 16);
    v += __shfl_xor(v, 32);
    if (lg == 0)
      l_part[(size_t)sp * (NB * NH * LQ) + bh * LQ + q0 + qs * 16 + lr] = v;
  }
  __syncthreads();
  // ---- 4-way sync among blocks sharing (b, qg) ----
  if (tid == 0) {
    __threadfence();  // publish l_part (device scope)
    int* fl = &flags[b * 16 + qg];
    __hip_atomic_fetch_add(fl, 1, __ATOMIC_ACQ_REL, __HIP_MEMORY_SCOPE_AGENT);
    while (__hip_atomic_load(fl, __ATOMIC_ACQUIRE, __HIP_MEMORY_SCOPE_AGENT) < SPLIT) {
    }
    __threadfence();
  }
  __syncthreads();

  float nlg[4];
  for (int qs = 0; qs < 4; ++qs) {
    float ls = 0.f;
    for (int s = 0; s < SPLIT; ++s)
      ls += l_part[(size_t)s * (NB * NH * LQ) + bh * LQ + q0 + qs * 16 + lr];
    nlg[qs] = -__builtin_amdgcn_logf(ls) - 3.0f;  // fold softmax/8
  }

  // ---- main: P (swizzled dbuf), PV, barrier, head-avg; 1 barrier/tile ----
  f32x4 cacc[4][4] = {};
  for (int t = 0; t < NT; ++t) {
    const int kv0 = t * 64;  // within this block's slice
    unsigned short (*Pb)[64][64] = P[t & 1];
    bf16x8 vf[4][2];
    for (int ds = 0; ds < 4; ++ds)
      for (int kk = 0; kk < 2; ++kk)
        vf[ds][kk] = *(const bf16x8*)(Vp + (size_t)(ds * 16 + lr) * LKV + kv0 +
                                      kk * 32 + lg * 8);
    for (int kh = 0; kh < 2; ++kh) {
      bf16x8 kA[2][2];
      for (int k2 = 0; k2 < 2; ++k2)
        for (int kk = 0; kk < 2; ++kk)
          kA[k2][kk] = *(const bf16x8*)(Kp + (size_t)(kv0 + (kh * 2 + k2) * 16 + lr) * HD +
                                        kk * 32 + lg * 8);
      f32x4 sacc[2][4] = {};
      for (int k2 = 0; k2 < 2; ++k2)
        for (int qs = 0; qs < 4; ++qs)
          sacc[k2][qs] = mfma16(kA[k2][1], qB[qs][1],
                                mfma16(kA[k2][0], qB[qs][0], sacc[k2][qs]));
      for (int k2 = 0; k2 < 2; ++k2)
        for (int qs = 0; qs < 4; ++qs) {
          const int q = qs * 16 + lr;
          const float p0 = __builtin_amdgcn_exp2f(sacc[k2][qs][0] + nlg[qs]);
          const float p1 = __builtin_amdgcn_exp2f(sacc[k2][qs][1] + nlg[qs]);
          const float p2 = __builtin_amdgcn_exp2f(sacc[k2][qs][2] + nlg[qs]);
          const float p3 = __builtin_amdgcn_exp2f(sacc[k2][qs][3] + nlg[qs]);
          uint2 w;
          w.x = cvt_pk_bf16(p0, p1);
          w.y = cvt_pk_bf16(p2, p3);
          const int col = ((kh * 2 + k2) * 16 + lg * 4) ^ ((q & 7) << 3);
          *(uint2*)&Pb[h][q][col] = w;
        }
    }
    // PV on own head's P (same-wave LDS dependency; no barrier needed)
    for (int kk = 0; kk < 2; ++kk) {
      bf16x8 pa[4];
      for (int qs = 0; qs < 4; ++qs) {
        const int q = qs * 16 + lr;
        pa[qs] = *(const bf16x8*)&Pb[h][q][(kk * 32 + lg * 8) ^ ((q & 7) << 3)];
      }
      for (int qs = 0; qs < 4; ++qs)
        for (int ds = 0; ds < 4; ++ds)
          cacc[qs][ds] = mfma16(pa[qs], vf[ds][kk], cacc[qs][ds]);
    }
    __syncthreads();  // all heads' P(t) visible
    // head-average -> attn_w (P already holds softmax/8)
    {
      const int qa = tid >> 3, La = tid & 7;
      const int col = (La * 8) ^ ((qa & 7) << 3);
      float2 s01 = {0.f, 0.f}, s23 = {0.f, 0.f}, s45 = {0.f, 0.f},
             s67 = {0.f, 0.f};
      for (int hh = 0; hh < NH; ++hh) {
        const uint4 v = *(const uint4*)&Pb[hh][qa][col];
        s01.x += __uint_as_float(v.x << 16);
        s01.y += __uint_as_float(v.x & 0xFFFF0000u);
        s23.x += __uint_as_float(v.y << 16);
        s23.y += __uint_as_float(v.y & 0xFFFF0000u);
        s45.x += __uint_as_float(v.z << 16);
        s45.y += __uint_as_float(v.z & 0xFFFF0000u);
        s67.x += __uint_as_float(v.w << 16);
        s67.y += __uint_as_float(v.w & 0xFFFF0000u);
      }
      float* op = attn_w + (size_t)(b * LQ + q0 + qa) * LKV + sp * SLICE + kv0 +
                  La * 8;
      float4 o0 = {s01.x, s01.y, s23.x, s23.y};
      float4 o1 = {s45.x, s45.y, s67.x, s67.y};
      *(float4*)op = o0;
      *(float4*)(op + 4) = o1;
    }
    // no second barrier: next tile writes P[(t+1)&1]
  }
  unsigned short* cp = ctxp + (size_t)sp * CPL;
  for (int qs = 0; qs < 4; ++qs)
    for (int ds = 0; ds < 4; ++ds)
      for (int r = 0; r < 4; ++r)
        cp[(size_t)(b * LQ + q0 + qs * 16 + lg * 4 + r) * E_DIM + h * HD +
           ds * 16 + lr] = f2b(cacc[qs][ds][r]);
}

// sum 4 bf16 ctx planes -> bf16 ctx
__global__ __launch_bounds__(256) void combine_ctx(
    const unsigned short* __restrict__ ctxp, unsigned short* __restrict__ ctxb) {
  const size_t i = (size_t)blockIdx.x * 256 + threadIdx.x;  // 8 elems/thread
  float2 s01 = {0.f, 0.f}, s23 = {0.f, 0.f}, s45 = {0.f, 0.f}, s67 = {0.f, 0.f};
  for (int pl = 0; pl < SPLIT; ++pl) {
    const uint4 v = ((const uint4*)(ctxp + pl * CPL))[i];
    s01.x += __uint_as_float(v.x << 16);
    s01.y += __uint_as_float(v.x & 0xFFFF0000u);
    s23.x += __uint_as_float(v.y << 16);
    s23.y += __uint_as_float(v.y & 0xFFFF0000u);
    s45.x += __uint_as_float(v.z << 16);
    s45.y += __uint_as_float(v.z & 0xFFFF0000u);
    s67.x += __uint_as_float(v.w << 16);
    s67.y += __uint_as_float(v.w & 0xFFFF0000u);
  }
  uint4 o;
  o.x = cvt_pk_bf16(s01.x, s01.y);
  o.y = cvt_pk_bf16(s23.x, s23.y);
  o.z = cvt_pk_bf16(s45.x, s45.y);
  o.w = cvt_pk_bf16(s67.x, s67.y);
  ((uint4*)ctxb)[i] = o;
}

// out = LN(query + attn_out) * gamma + beta ; one block per row
__global__ __launch_bounds__(256) void ln_kernel(
    const float* __restrict__ q, const float* __restrict__ ao,
    const float* __restrict__ gamma, const float* __restrict__ beta,
    float* __restrict__ out) {
  const int row = blockIdx.x;
  const int tid = threadIdx.x;
  const size_t base = (size_t)row * E_DIM;
  const float x0 = q[base + tid] + ao[base + tid];
  const float x1 = q[base + 256 + tid] + ao[base + 256 + tid];
  float s = x0 + x1, ss = x0 * x0 + x1 * x1;
  for (int off = 32; off >= 1; off >>= 1) {
    s += __shfl_down(s, off);
    ss += __shfl_down(ss, off);
  }
  __shared__ float ps[4], pss[4];
  if ((tid & 63) == 0) {
    ps[tid >> 6] = s;
    pss[tid >> 6] = ss;
  }
  __syncthreads();
  s = ps[0] + ps[1] + ps[2] + ps[3];
  ss = pss[0] + pss[1] + pss[2] + pss[3];
  const float mu = s * (1.f / E_DIM);
  float var = ss * (1.f / E_DIM) - mu * mu;
  var = fmaxf(var, 0.f);
  const float rstd = rsqrtf(var + 1e-5f);
  out[base + tid] = (x0 - mu) * rstd * gamma[tid] + beta[tid];
  out[base + 256 + tid] = (x1 - mu) * rstd * gamma[256 + tid] + beta[256 + tid];
}

}  // namespace

extern "C" void kernel_launch(void* const* d_in, const int* in_sizes, int n_in,
                              void* d_out, int out_size, void* d_ws, size_t ws_size,
                              hipStream_t stream) {
  const float* query = (const float*)d_in[0];
  const float* key_value = (const float*)d_in[1];
  const float* w_q = (const float*)d_in[2];
  const float* w_k = (const float*)d_in[3];
  const float* w_v = (const float*)d_in[4];
  const float* b_q = (const float*)d_in[5];
  const float* b_k = (const float*)d_in[6];
  const float* b_v = (const float*)d_in[7];
  const float* w_o = (const float*)d_in[8];
  const float* b_o = (const float*)d_in[9];
  const float* ln_g = (const float*)d_in[10];
  const float* ln_b = (const float*)d_in[11];

  // ws layout in u16 units (65 MB peak):
  // Qb[0,2M) Kb[2M,10M) Vt[10M,18M) l_part+flags[18M,18.5M) Wb[18.5M,19.5M)
  // ao(f32)[19.5M,23.5M) KVb[23.5M,31.5M) Qxb[31.5M,32.5M)
  // ctxp aliases KVb [23.5M,31.5M) (4 planes; KVb dead after GEMMs)
  // ctxb aliases Qb [0,2M)         (Qb dead after attn_fused)
  unsigned short* Qb = (unsigned short*)d_ws;
  unsigned short* Kb = Qb + (size_t)2097152;
  unsigned short* Vt = Kb + (size_t)8388608;
  float* l_part = (float*)(Vt + (size_t)8388608);
  int* flags = (int*)(l_part + (size_t)SPLIT * NB * NH * LQ);  // 64 ints
  unsigned short* Wb = (unsigned short*)(l_part + 262144);
  float* ao = (float*)(Wb + 1048576);
  unsigned short* KVb = (unsigned short*)(ao + 2097152);
  unsigned short* Qxb = KVb + (size_t)8388608;
  unsigned short* ctxp = KVb;  // alias (KVb dead after GEMMs)
  unsigned short* ctxb = Qb;   // alias (Qb dead after attn_fused)

  float* out = (float*)d_out;
  float* attn_w = out + (size_t)NB * LQ * E_DIM;

  const float qscale = 0.125f * 1.44269504088896340736f;  // 1/sqrt(64)*log2(e)

  hipMemsetAsync(flags, 0, sizeof(int) * NB * 16, stream);

  cvt_all<<<dim3(5632), dim3(256), 0, stream>>>(query, key_value, w_q, w_k, w_v,
                                                w_o, Qxb, KVb, Wb);

  // Q projection: 64x128 tile -> 256 blocks (full CU coverage)
  gemm64<0><<<dim3(4, 64), dim3(256), 0, stream>>>(Qxb, Wb, b_q, Qb, LQ, qscale);
  // K and V projections: 128x128 tile, 512 blocks each (R9 structure)
  gemm_bf16<0><<<dim3(4, 128), dim3(256), 0, stream>>>(KVb, Wb + 262144, b_k, Kb,
                                                       LKV, 1.0f);
  // V pre-scaled x8 (pairs with P/8 so PV is exact; avg needs no x0.125)
  gemm_bf16<1><<<dim3(4, 128), dim3(256), 0, stream>>>(KVb, Wb + 524288, b_v, Vt,
                                                       LKV, 8.0f);

  attn_fused<<<dim3(16, NB, SPLIT), dim3(512), 0, stream>>>(Qb, Kb, Vt, l_part,
                                                            flags, attn_w, ctxp);
  combine_ctx<<<dim3(1024), dim3(256), 0, stream>>>(ctxp, ctxb);
  // O projection: 64x128 tile -> 256 blocks
  gemm64<2><<<dim3(4, 64), dim3(256), 0, stream>>>(ctxb, Wb + 786432, b_o, ao,
                                                   LQ, 1.0f);
  ln_kernel<<<dim3(NB * LQ), dim3(256), 0, stream>>>(query, ao, ln_g, ln_b, out);
}